// Round 4
// baseline (959.747 us; speedup 1.0000x reference)
//
#include <hip/hip_runtime.h>
#include <cstdint>
#include <cstddef>

#define NPOINT 512
#define NSAMPLE 32
#define NPB 8192  // points per batch

// Inputs: float32 (per reference setup_inputs).
// Outputs: float32 flat concat in return order (new_xyz, new_idx,
// new_features, sample_ids); harness compares vs bf16-quantized np ref with
// a ~2%-of-max absmax threshold. Indices must be EXACT (written as f32).
__device__ __forceinline__ unsigned short f2bf(float f) {
  unsigned int u = __float_as_uint(f);
  unsigned int r = u + 0x7FFFu + ((u >> 16) & 1u);  // RNE
  return (unsigned short)(r >> 16);
}
__device__ __forceinline__ unsigned long long shfl_xor_u64(unsigned long long v, int off) {
  int lo = __shfl_xor((int)(unsigned int)(v & 0xFFFFFFFFull), off);
  int hi = __shfl_xor((int)(unsigned int)(v >> 32), off);
  return (((unsigned long long)(unsigned int)hi) << 32) | (unsigned int)lo;
}

// ---------------------------------------------------------------- FPS
// One block (512 thr) per batch. Each thread owns 16 contiguous points in
// registers. Exact numpy-f32 distance: ((dx*dx+dy*dy)+dz*dz), no contraction.
// Argmax key: (distBits<<32)|(8191-idx): max -> max dist, tie -> min idx.
__global__ __launch_bounds__(512) void k_fps(const float* __restrict__ xyz,
                                             float* __restrict__ out_xyz,
                                             float* __restrict__ out_idx) {
  const int b = blockIdx.x;
  const int t = threadIdx.x;
  const float* xb = xyz + (size_t)b * NPB * 3;

  float px[16], py[16], pz[16], dist[16];
  {
    const float4* gp = reinterpret_cast<const float4*>(xb + (size_t)t * 48);
    float comp[48];
#pragma unroll
    for (int v = 0; v < 12; ++v) {
      float4 r = gp[v];
      comp[v * 4 + 0] = r.x;
      comp[v * 4 + 1] = r.y;
      comp[v * 4 + 2] = r.z;
      comp[v * 4 + 3] = r.w;
    }
#pragma unroll
    for (int j = 0; j < 16; ++j) {
      px[j] = comp[3 * j + 0];
      py[j] = comp[3 * j + 1];
      pz[j] = comp[3 * j + 2];
      dist[j] = 1e10f;
    }
  }

  __shared__ unsigned long long sKey[8];
  __shared__ float sX[8], sY[8], sZ[8];
  __shared__ float qB[3];

  if (t == 0) {  // selection 0 is always index 0
    out_idx[b * NPOINT + 0] = 0.0f;
    size_t o = (size_t)(b * NPOINT) * 3;
    out_xyz[o + 0] = px[0];
    out_xyz[o + 1] = py[0];
    out_xyz[o + 2] = pz[0];
    qB[0] = px[0]; qB[1] = py[0]; qB[2] = pz[0];
  }
  __syncthreads();

  const int wid = t >> 6;
  const int lane = t & 63;

  for (int it = 1; it < NPOINT; ++it) {
    const float qx = qB[0], qy = qB[1], qz = qB[2];
    float best = -1.0f;
    int bi = 0;
#pragma unroll
    for (int j = 0; j < 16; ++j) {
      float dx = __fsub_rn(px[j], qx);
      float dy = __fsub_rn(py[j], qy);
      float dz = __fsub_rn(pz[j], qz);
      float d2 = __fadd_rn(__fadd_rn(__fmul_rn(dx, dx), __fmul_rn(dy, dy)), __fmul_rn(dz, dz));
      float nd = fminf(dist[j], d2);
      dist[j] = nd;
      if (nd > best) { best = nd; bi = t * 16 + j; }  // ascending idx per thread
    }
    unsigned long long key =
        (((unsigned long long)__float_as_uint(best)) << 32) | (unsigned int)(8191 - bi);
#pragma unroll
    for (int off = 32; off >= 1; off >>= 1) {
      unsigned long long ok = shfl_xor_u64(key, off);
      if (ok > key) key = ok;
    }
    const int wbi = 8191 - (int)(key & 0xFFFFFFFFull);
    if (t == (wbi >> 4)) {  // owner of this wave's winner: publish coords
      const int j = wbi & 15;
      float sx_ = 0.f, sy_ = 0.f, sz_ = 0.f;
      switch (j) {
        case 0:  sx_ = px[0];  sy_ = py[0];  sz_ = pz[0];  break;
        case 1:  sx_ = px[1];  sy_ = py[1];  sz_ = pz[1];  break;
        case 2:  sx_ = px[2];  sy_ = py[2];  sz_ = pz[2];  break;
        case 3:  sx_ = px[3];  sy_ = py[3];  sz_ = pz[3];  break;
        case 4:  sx_ = px[4];  sy_ = py[4];  sz_ = pz[4];  break;
        case 5:  sx_ = px[5];  sy_ = py[5];  sz_ = pz[5];  break;
        case 6:  sx_ = px[6];  sy_ = py[6];  sz_ = pz[6];  break;
        case 7:  sx_ = px[7];  sy_ = py[7];  sz_ = pz[7];  break;
        case 8:  sx_ = px[8];  sy_ = py[8];  sz_ = pz[8];  break;
        case 9:  sx_ = px[9];  sy_ = py[9];  sz_ = pz[9];  break;
        case 10: sx_ = px[10]; sy_ = py[10]; sz_ = pz[10]; break;
        case 11: sx_ = px[11]; sy_ = py[11]; sz_ = pz[11]; break;
        case 12: sx_ = px[12]; sy_ = py[12]; sz_ = pz[12]; break;
        case 13: sx_ = px[13]; sy_ = py[13]; sz_ = pz[13]; break;
        case 14: sx_ = px[14]; sy_ = py[14]; sz_ = pz[14]; break;
        default: sx_ = px[15]; sy_ = py[15]; sz_ = pz[15]; break;
      }
      sX[wid] = sx_; sY[wid] = sy_; sZ[wid] = sz_;
    }
    if (lane == 0) sKey[wid] = key;
    __syncthreads();
    if (t < 64) {
      unsigned long long kk = (lane < 8) ? sKey[lane] : 0ull;
      int slot = lane;
#pragma unroll
      for (int off = 4; off >= 1; off >>= 1) {
        unsigned long long ok = shfl_xor_u64(kk, off);
        int os = __shfl_xor(slot, off);
        if (ok > kk) { kk = ok; slot = os; }
      }
      if (t == 0) {
        const int gbi = 8191 - (int)(kk & 0xFFFFFFFFull);
        out_idx[b * NPOINT + it] = (float)gbi;
        size_t o = (size_t)(b * NPOINT + it) * 3;
        float gx = sX[slot], gy = sY[slot], gz = sZ[slot];
        out_xyz[o + 0] = gx;
        out_xyz[o + 1] = gy;
        out_xyz[o + 2] = gz;
        qB[0] = gx; qB[1] = gy; qB[2] = gz;
      }
    }
    __syncthreads();
  }
}

// ---------------------------------------------------------- feature transpose
// features f32 [64][Ntot] -> feat_t bf16 [Ntot][64] (contiguous per point;
// bf16 fine: features only feed the MLP, threshold is ~2% of max)
__global__ __launch_bounds__(256) void k_transpose(const float* __restrict__ in,
                                                   unsigned short* __restrict__ out,
                                                   int Ntot) {
  __shared__ __align__(16) unsigned short tile[64][65];
  const int t = threadIdx.x;
  const int n0 = blockIdx.x * 64;
#pragma unroll
  for (int i = 0; i < 16; ++i) {
    int c = i * 4 + (t >> 6);
    int n = t & 63;
    tile[c][n] = f2bf(in[(size_t)c * Ntot + n0 + n]);
  }
  __syncthreads();
#pragma unroll
  for (int i = 0; i < 16; ++i) {
    int n = i * 4 + (t >> 6);
    int c = t & 63;
    out[(size_t)(n0 + n) * 64 + c] = tile[c][n];
  }
}

// ---------------------------------------------------------------- ball query
// One wave per center (8 waves/block). xyz read from global (coalesced,
// L2-resident: 96 KB/batch reused by 64 blocks). Ordered compaction of the
// first NSAMPLE in-ball ids via ballot+popcount. Exact f32 math, strict <.
__global__ __launch_bounds__(512) void k_ball(const float* __restrict__ xyz,
                                              const float* __restrict__ fps_idx_f,
                                              float* __restrict__ sids_f) {
  __shared__ int slots[8 * NSAMPLE];
  const int b = blockIdx.x >> 6;
  const int cbase = (blockIdx.x & 63) * 8;
  const int t = threadIdx.x;
  const float* xb = xyz + (size_t)b * NPB * 3;

  const int w = t >> 6, lane = t & 63;
  const int c_local = cbase + w;
  const int ci = (int)fps_idx_f[b * NPOINT + c_local];
  const float cx = xb[ci * 3 + 0];
  const float cy = xb[ci * 3 + 1];
  const float cz = xb[ci * 3 + 2];
  const float R2 = 0.01f;  // f32(0.1*0.1) under numpy weak-scalar promotion

  int cnt = 0;
  for (int r = 0; r < NPB / 64 && cnt < NSAMPLE; ++r) {
    const int p = r * 64 + lane;
    float dx = __fsub_rn(xb[p * 3 + 0], cx);
    float dy = __fsub_rn(xb[p * 3 + 1], cy);
    float dz = __fsub_rn(xb[p * 3 + 2], cz);
    float d2 = __fadd_rn(__fadd_rn(__fmul_rn(dx, dx), __fmul_rn(dy, dy)), __fmul_rn(dz, dz));
    const bool inb = d2 < R2;
    const unsigned long long m = __ballot(inb);
    if (inb) {
      int pos = cnt + (int)__popcll(m & ((1ull << lane) - 1ull));
      if (pos < NSAMPLE) slots[w * NSAMPLE + pos] = p;
    }
    cnt += (int)__popcll(m);
  }
  if (lane < NSAMPLE) {
    const int first = (cnt > 0) ? slots[w * NSAMPLE] : 0;
    const int v = (lane < cnt) ? slots[w * NSAMPLE + lane] : first;
    sids_f[((size_t)(b * NPOINT + c_local)) * NSAMPLE + lane] = (float)v;
  }
}

// ------------------------------------------------------- gather + MLP + max
// 32 lanes = 32 samples, 2 centers per wave, 8 centers per 256-thr block.
// W0/W2 f32 in LDS, W1 bf16 in LDS (~59 KB total). h1/h2 in registers.
// useT: gather features from transposed bf16 ws buffer vs direct f32 [C][N].
__global__ __launch_bounds__(256) void k_mlp(const float* __restrict__ xyz,
                                             const float* __restrict__ feat,
                                             const unsigned short* __restrict__ feat_t,
                                             const float* __restrict__ fps_idx_f,
                                             const float* __restrict__ sids_f,
                                             const float* __restrict__ w0g,
                                             const float* __restrict__ b0g,
                                             const float* __restrict__ w1g,
                                             const float* __restrict__ b1g,
                                             const float* __restrict__ w2g,
                                             const float* __restrict__ b2g,
                                             float* __restrict__ out_feat,
                                             int Ntot, int useT) {
  __shared__ __align__(16) float W0s[64 * 68];            // padded rows (c 67 = 0)
  __shared__ __align__(16) unsigned short W1s[64 * 64];   // bf16
  __shared__ __align__(16) float W2s[128 * 64];
  __shared__ float b0s[64], b1s[64], b2s[128];
  const int t = threadIdx.x;
  for (int i = t; i < 64 * 68; i += 256) {
    int r = i / 68, c = i - r * 68;
    W0s[i] = (c < 67) ? w0g[r * 67 + c] : 0.0f;
  }
  for (int i = t; i < 64 * 64; i += 256) W1s[i] = f2bf(w1g[i]);
  for (int i = t; i < 128 * 64; i += 256) W2s[i] = w2g[i];
  if (t < 64) b0s[t] = b0g[t];
  if (t < 64) b1s[t] = b1g[t];
  if (t < 128) b2s[t] = b2g[t];
  __syncthreads();

  const int b = blockIdx.x >> 6;
  const int c_local = (blockIdx.x & 63) * 8 + (t >> 5);
  const int s = t & 31;
  const int ci = (int)fps_idx_f[b * NPOINT + c_local];
  const float cx = xyz[((size_t)b * NPB + ci) * 3 + 0];
  const float cy = xyz[((size_t)b * NPB + ci) * 3 + 1];
  const float cz = xyz[((size_t)b * NPB + ci) * 3 + 2];
  const int id = (int)sids_f[((size_t)(b * NPOINT + c_local)) * NSAMPLE + s];

  float g[68];
  {
    const size_t pb = ((size_t)b * NPB + id) * 3;
    g[0] = __fsub_rn(xyz[pb + 0], cx);
    g[1] = __fsub_rn(xyz[pb + 1], cy);
    g[2] = __fsub_rn(xyz[pb + 2], cz);
    if (useT) {
      const uint4* fp = reinterpret_cast<const uint4*>(feat_t + ((size_t)b * NPB + id) * 64);
#pragma unroll
      for (int v = 0; v < 8; ++v) {
        uint4 r = fp[v];
        unsigned int vs[4] = {r.x, r.y, r.z, r.w};
#pragma unroll
        for (int q = 0; q < 4; ++q) {
          g[3 + v * 8 + q * 2 + 0] = __uint_as_float(vs[q] << 16);
          g[3 + v * 8 + q * 2 + 1] = __uint_as_float(vs[q] & 0xFFFF0000u);
        }
      }
    } else {
      const float* col = feat + (size_t)(b * NPB + id);
#pragma unroll 8
      for (int c = 0; c < 64; ++c) g[3 + c] = col[(size_t)c * Ntot];
    }
    g[67] = 0.0f;
  }

  float h1[64];
#pragma unroll
  for (int o = 0; o < 64; ++o) {
    float acc = b0s[o];
    const float4* wp = reinterpret_cast<const float4*>(&W0s[o * 68]);
#pragma unroll
    for (int c4 = 0; c4 < 17; ++c4) {
      float4 wv = wp[c4];
      acc += wv.x * g[c4 * 4 + 0];
      acc += wv.y * g[c4 * 4 + 1];
      acc += wv.z * g[c4 * 4 + 2];
      acc += wv.w * g[c4 * 4 + 3];
    }
    h1[o] = fmaxf(acc, 0.0f);
  }
  float h2[64];
#pragma unroll
  for (int o = 0; o < 64; ++o) {
    float acc = b1s[o];
    const uint2* wp = reinterpret_cast<const uint2*>(&W1s[o * 64]);
#pragma unroll
    for (int c4 = 0; c4 < 16; ++c4) {
      uint2 u = wp[c4];
      acc += __uint_as_float(u.x << 16) * h1[c4 * 4 + 0];
      acc += __uint_as_float(u.x & 0xFFFF0000u) * h1[c4 * 4 + 1];
      acc += __uint_as_float(u.y << 16) * h1[c4 * 4 + 2];
      acc += __uint_as_float(u.y & 0xFFFF0000u) * h1[c4 * 4 + 3];
    }
    h2[o] = fmaxf(acc, 0.0f);
  }
#pragma unroll 1
  for (int o = 0; o < 128; ++o) {
    float acc = b2s[o];
    const float4* wp = reinterpret_cast<const float4*>(&W2s[o * 64]);
#pragma unroll
    for (int c4 = 0; c4 < 16; ++c4) {
      float4 wv = wp[c4];
      acc += wv.x * h2[c4 * 4 + 0];
      acc += wv.y * h2[c4 * 4 + 1];
      acc += wv.z * h2[c4 * 4 + 2];
      acc += wv.w * h2[c4 * 4 + 3];
    }
    float v = fmaxf(acc, 0.0f);
#pragma unroll
    for (int off = 16; off >= 1; off >>= 1) v = fmaxf(v, __shfl_xor(v, off));
    if (s == 0) out_feat[((size_t)b * 128 + o) * NPOINT + c_local] = v;
  }
}

// ------------------------------------------------------------------- launch
extern "C" void kernel_launch(void* const* d_in, const int* in_sizes, int n_in,
                              void* d_out, int out_size, void* d_ws, size_t ws_size,
                              hipStream_t stream) {
  (void)n_in; (void)out_size;
  const float* xyz = (const float*)d_in[0];
  const float* feat = (const float*)d_in[1];
  // d_in[2] = num_points (8192, fixed by setup)
  const float* w0 = (const float*)d_in[3];
  const float* b0 = (const float*)d_in[4];
  const float* w1 = (const float*)d_in[5];
  const float* b1 = (const float*)d_in[6];
  const float* w2 = (const float*)d_in[7];
  const float* b2 = (const float*)d_in[8];

  const int Ntot = in_sizes[0] / 3;   // 65536
  const int B = Ntot / NPB;           // 8

  float* out = (float*)d_out;
  float* o_xyz = out;                                    // [B,512,3]
  float* o_idx = o_xyz + (size_t)B * NPOINT * 3;         // [B,512]
  float* o_feat = o_idx + (size_t)B * NPOINT;            // [B,128,512]
  float* o_sids = o_feat + (size_t)B * 128 * NPOINT;     // [B,512,32]

  // Workspace: only the transposed-features buffer (bf16), only if it fits.
  const size_t ft_bytes = (size_t)Ntot * 64 * 2;         // 8 MB
  const int useT = (ws_size >= ft_bytes) ? 1 : 0;
  unsigned short* ft_ws = (unsigned short*)d_ws;

  if (useT) {
    k_transpose<<<dim3(Ntot / 64), dim3(256), 0, stream>>>(feat, ft_ws, Ntot);
  }
  k_fps<<<dim3(B), dim3(512), 0, stream>>>(xyz, o_xyz, o_idx);
  k_ball<<<dim3(B * 64), dim3(512), 0, stream>>>(xyz, o_idx, o_sids);
  k_mlp<<<dim3(B * 64), dim3(256), 0, stream>>>(xyz, feat, ft_ws, o_idx, o_sids,
                                                w0, b0, w1, b1, w2, b2, o_feat,
                                                Ntot, useT);
}

// Round 5
// 875.695 us; speedup vs baseline: 1.0960x; 1.0960x over previous
//
#include <hip/hip_runtime.h>
#include <cstdint>
#include <cstddef>

#define NPOINT 512
#define NSAMPLE 32
#define NPB 8192  // points per batch

// Inputs: float32. Outputs: float32 flat concat (new_xyz, new_idx,
// new_features, sample_ids). Selection math (FPS argmax, ball d2<r2) must be
// bit-exact vs numpy f32: __f*_rn ops, no FMA contraction, exact tie-breaks.
__device__ __forceinline__ unsigned short f2bf(float f) {
  unsigned int u = __float_as_uint(f);
  unsigned int r = u + 0x7FFFu + ((u >> 16) & 1u);  // RNE
  return (unsigned short)(r >> 16);
}

// ---------------------------------------------------------------- FPS
// One block (512 thr) per batch; thread t owns points [t*16, t*16+16) in
// registers. Per iteration: exact dist update + local argmax; wave reduces
// f32 max via 6 shuffles; owner lane (lowest tied lane = smallest index)
// publishes {dist, idx, xyz} to parity-buffered LDS; ONE barrier; every
// thread scans the 8 wave slots (strict > keeps smallest wid = smallest
// index) and reads next q straight from the winning slot.
__global__ __launch_bounds__(512) void k_fps(const float* __restrict__ xyz,
                                             float* __restrict__ out_xyz,
                                             float* __restrict__ out_idx) {
  const int b = blockIdx.x;
  const int t = threadIdx.x;
  const float* xb = xyz + (size_t)b * NPB * 3;

  float px[16], py[16], pz[16], dist[16];
  {
    const float4* gp = reinterpret_cast<const float4*>(xb + (size_t)t * 48);
    float comp[48];
#pragma unroll
    for (int v = 0; v < 12; ++v) {
      float4 r = gp[v];
      comp[v * 4 + 0] = r.x;
      comp[v * 4 + 1] = r.y;
      comp[v * 4 + 2] = r.z;
      comp[v * 4 + 3] = r.w;
    }
#pragma unroll
    for (int j = 0; j < 16; ++j) {
      px[j] = comp[3 * j + 0];
      py[j] = comp[3 * j + 1];
      pz[j] = comp[3 * j + 2];
      dist[j] = 1e10f;
    }
  }

  __shared__ __align__(16) float sD[2][8];
  __shared__ int sI[2][8];
  __shared__ float sX[2][8], sY[2][8], sZ[2][8];

  const int wid = t >> 6;
  const int lane = t & 63;

  // selection 0 = index 0; q broadcast via (L2-hot) global read by all lanes
  float qx = xb[0], qy = xb[1], qz = xb[2];
  if (t == 0) {
    out_idx[b * NPOINT + 0] = 0.0f;
    size_t o = (size_t)(b * NPOINT) * 3;
    out_xyz[o + 0] = qx; out_xyz[o + 1] = qy; out_xyz[o + 2] = qz;
  }

  for (int it = 1; it < NPOINT; ++it) {
    float best = -1.0f;
    int bi = 0;  // local j of best (first max => smallest index)
#pragma unroll
    for (int j = 0; j < 16; ++j) {
      float dx = __fsub_rn(px[j], qx);
      float dy = __fsub_rn(py[j], qy);
      float dz = __fsub_rn(pz[j], qz);
      float d2 = __fadd_rn(__fadd_rn(__fmul_rn(dx, dx), __fmul_rn(dy, dy)), __fmul_rn(dz, dz));
      float nd = fminf(dist[j], d2);
      dist[j] = nd;
      if (nd > best) { best = nd; bi = j; }
    }
    // wave-level f32 max (all lanes converge to wmax)
    float wmax = best;
#pragma unroll
    for (int off = 32; off >= 1; off >>= 1) wmax = fmaxf(wmax, __shfl_xor(wmax, off));
    const unsigned long long m = __ballot(best == wmax);
    const int p = it & 1;
    if (lane == (int)(__ffsll((unsigned long long)m) - 1)) {  // lowest tied lane
      sD[p][wid] = wmax;
      sI[p][wid] = t * 16 + bi;
      float sx_, sy_, sz_;
      switch (bi) {
        case 0:  sx_ = px[0];  sy_ = py[0];  sz_ = pz[0];  break;
        case 1:  sx_ = px[1];  sy_ = py[1];  sz_ = pz[1];  break;
        case 2:  sx_ = px[2];  sy_ = py[2];  sz_ = pz[2];  break;
        case 3:  sx_ = px[3];  sy_ = py[3];  sz_ = pz[3];  break;
        case 4:  sx_ = px[4];  sy_ = py[4];  sz_ = pz[4];  break;
        case 5:  sx_ = px[5];  sy_ = py[5];  sz_ = pz[5];  break;
        case 6:  sx_ = px[6];  sy_ = py[6];  sz_ = pz[6];  break;
        case 7:  sx_ = px[7];  sy_ = py[7];  sz_ = pz[7];  break;
        case 8:  sx_ = px[8];  sy_ = py[8];  sz_ = pz[8];  break;
        case 9:  sx_ = px[9];  sy_ = py[9];  sz_ = pz[9];  break;
        case 10: sx_ = px[10]; sy_ = py[10]; sz_ = pz[10]; break;
        case 11: sx_ = px[11]; sy_ = py[11]; sz_ = pz[11]; break;
        case 12: sx_ = px[12]; sy_ = py[12]; sz_ = pz[12]; break;
        case 13: sx_ = px[13]; sy_ = py[13]; sz_ = pz[13]; break;
        case 14: sx_ = px[14]; sy_ = py[14]; sz_ = pz[14]; break;
        default: sx_ = px[15]; sy_ = py[15]; sz_ = pz[15]; break;
      }
      sX[p][wid] = sx_; sY[p][wid] = sy_; sZ[p][wid] = sz_;
    }
    __syncthreads();  // the only barrier per iteration
    // every thread scans the 8 wave winners (strict > => smallest wid on tie)
    float bd = sD[p][0];
    int bw = 0;
#pragma unroll
    for (int w = 1; w < 8; ++w) {
      float d = sD[p][w];
      if (d > bd) { bd = d; bw = w; }
    }
    const int gbi = sI[p][bw];
    qx = sX[p][bw]; qy = sY[p][bw]; qz = sZ[p][bw];
    if (t == 0) {
      out_idx[b * NPOINT + it] = (float)gbi;
      size_t o = (size_t)(b * NPOINT + it) * 3;
      out_xyz[o + 0] = qx; out_xyz[o + 1] = qy; out_xyz[o + 2] = qz;
    }
  }
}

// ---------------------------------------------------------- feature transpose
// features f32 [64][Ntot] -> feat_t bf16 [Ntot][64]
__global__ __launch_bounds__(256) void k_transpose(const float* __restrict__ in,
                                                   unsigned short* __restrict__ out,
                                                   int Ntot) {
  __shared__ __align__(16) unsigned short tile[64][65];
  const int t = threadIdx.x;
  const int n0 = blockIdx.x * 64;
#pragma unroll
  for (int i = 0; i < 16; ++i) {
    int c = i * 4 + (t >> 6);
    int n = t & 63;
    tile[c][n] = f2bf(in[(size_t)c * Ntot + n0 + n]);
  }
  __syncthreads();
#pragma unroll
  for (int i = 0; i < 16; ++i) {
    int n = i * 4 + (t >> 6);
    int c = t & 63;
    out[(size_t)(n0 + n) * 64 + c] = tile[c][n];
  }
}

// ---------------------------------------------------------------- ball query
// One wave per center (8 waves/block). Fixed 64 rounds x 2 points/lane: no
// data-dependent loop condition, so loads pipeline across rounds. Ordered
// compaction via ballot+popcount (first-64 sub-block before second-64 keeps
// index order). Exact f32 math, strict <.
__global__ __launch_bounds__(512) void k_ball(const float* __restrict__ xyz,
                                              const float* __restrict__ fps_idx_f,
                                              float* __restrict__ sids_f) {
  __shared__ int slots[8 * NSAMPLE];
  const int b = blockIdx.x >> 6;
  const int cbase = (blockIdx.x & 63) * 8;
  const int t = threadIdx.x;
  const float* xb = xyz + (size_t)b * NPB * 3;

  const int w = t >> 6, lane = t & 63;
  const int c_local = cbase + w;
  const int ci = (int)fps_idx_f[b * NPOINT + c_local];
  const float cx = xb[ci * 3 + 0];
  const float cy = xb[ci * 3 + 1];
  const float cz = xb[ci * 3 + 2];
  const float R2 = 0.01f;  // f32(0.1*0.1), numpy weak-scalar promotion
  const unsigned long long below = (1ull << lane) - 1ull;

  int cnt = 0;
#pragma unroll 4
  for (int r = 0; r < 64; ++r) {
    const int p0 = r * 128 + lane;
    const int p1 = p0 + 64;
    float ax = xb[p0 * 3 + 0], ay = xb[p0 * 3 + 1], az = xb[p0 * 3 + 2];
    float bx = xb[p1 * 3 + 0], by = xb[p1 * 3 + 1], bz = xb[p1 * 3 + 2];
    float dxa = __fsub_rn(ax, cx), dya = __fsub_rn(ay, cy), dza = __fsub_rn(az, cz);
    float dxb = __fsub_rn(bx, cx), dyb = __fsub_rn(by, cy), dzb = __fsub_rn(bz, cz);
    float d2a = __fadd_rn(__fadd_rn(__fmul_rn(dxa, dxa), __fmul_rn(dya, dya)), __fmul_rn(dza, dza));
    float d2b = __fadd_rn(__fadd_rn(__fmul_rn(dxb, dxb), __fmul_rn(dyb, dyb)), __fmul_rn(dzb, dzb));
    const bool i0 = d2a < R2;
    const bool i1 = d2b < R2;
    const unsigned long long m0 = __ballot(i0);
    if (i0) {
      int pos = cnt + (int)__popcll(m0 & below);
      if (pos < NSAMPLE) slots[w * NSAMPLE + pos] = p0;
    }
    cnt += (int)__popcll(m0);
    const unsigned long long m1 = __ballot(i1);
    if (i1) {
      int pos = cnt + (int)__popcll(m1 & below);
      if (pos < NSAMPLE) slots[w * NSAMPLE + pos] = p1;
    }
    cnt += (int)__popcll(m1);
  }
  if (lane < NSAMPLE) {
    const int first = (cnt > 0) ? slots[w * NSAMPLE] : 0;
    const int v = (lane < cnt) ? slots[w * NSAMPLE + lane] : first;
    sids_f[((size_t)(b * NPOINT + c_local)) * NSAMPLE + lane] = (float)v;
  }
}

// ------------------------------------------------------- gather + MLP + max
// 32 lanes = 32 samples, 2 centers per wave, 8 centers per 256-thr block.
// W0/W2 f32 in LDS, W1 bf16 in LDS (~59 KB). h1/h2 in registers.
__global__ __launch_bounds__(256) void k_mlp(const float* __restrict__ xyz,
                                             const float* __restrict__ feat,
                                             const unsigned short* __restrict__ feat_t,
                                             const float* __restrict__ fps_idx_f,
                                             const float* __restrict__ sids_f,
                                             const float* __restrict__ w0g,
                                             const float* __restrict__ b0g,
                                             const float* __restrict__ w1g,
                                             const float* __restrict__ b1g,
                                             const float* __restrict__ w2g,
                                             const float* __restrict__ b2g,
                                             float* __restrict__ out_feat,
                                             int Ntot, int useT) {
  __shared__ __align__(16) float W0s[64 * 68];            // padded rows (c 67 = 0)
  __shared__ __align__(16) unsigned short W1s[64 * 64];   // bf16
  __shared__ __align__(16) float W2s[128 * 64];
  __shared__ float b0s[64], b1s[64], b2s[128];
  const int t = threadIdx.x;
  for (int i = t; i < 64 * 68; i += 256) {
    int r = i / 68, c = i - r * 68;
    W0s[i] = (c < 67) ? w0g[r * 67 + c] : 0.0f;
  }
  for (int i = t; i < 64 * 64; i += 256) W1s[i] = f2bf(w1g[i]);
  for (int i = t; i < 128 * 64; i += 256) W2s[i] = w2g[i];
  if (t < 64) b0s[t] = b0g[t];
  if (t < 64) b1s[t] = b1g[t];
  if (t < 128) b2s[t] = b2g[t];
  __syncthreads();

  const int b = blockIdx.x >> 6;
  const int c_local = (blockIdx.x & 63) * 8 + (t >> 5);
  const int s = t & 31;
  const int ci = (int)fps_idx_f[b * NPOINT + c_local];
  const float cx = xyz[((size_t)b * NPB + ci) * 3 + 0];
  const float cy = xyz[((size_t)b * NPB + ci) * 3 + 1];
  const float cz = xyz[((size_t)b * NPB + ci) * 3 + 2];
  const int id = (int)sids_f[((size_t)(b * NPOINT + c_local)) * NSAMPLE + s];

  float g[68];
  {
    const size_t pb = ((size_t)b * NPB + id) * 3;
    g[0] = __fsub_rn(xyz[pb + 0], cx);
    g[1] = __fsub_rn(xyz[pb + 1], cy);
    g[2] = __fsub_rn(xyz[pb + 2], cz);
    if (useT) {
      const uint4* fp = reinterpret_cast<const uint4*>(feat_t + ((size_t)b * NPB + id) * 64);
#pragma unroll
      for (int v = 0; v < 8; ++v) {
        uint4 r = fp[v];
        unsigned int vs[4] = {r.x, r.y, r.z, r.w};
#pragma unroll
        for (int q = 0; q < 4; ++q) {
          g[3 + v * 8 + q * 2 + 0] = __uint_as_float(vs[q] << 16);
          g[3 + v * 8 + q * 2 + 1] = __uint_as_float(vs[q] & 0xFFFF0000u);
        }
      }
    } else {
      const float* col = feat + (size_t)(b * NPB + id);
#pragma unroll 8
      for (int c = 0; c < 64; ++c) g[3 + c] = col[(size_t)c * Ntot];
    }
    g[67] = 0.0f;
  }

  float h1[64];
#pragma unroll
  for (int o = 0; o < 64; ++o) {
    float acc = b0s[o];
    const float4* wp = reinterpret_cast<const float4*>(&W0s[o * 68]);
#pragma unroll
    for (int c4 = 0; c4 < 17; ++c4) {
      float4 wv = wp[c4];
      acc += wv.x * g[c4 * 4 + 0];
      acc += wv.y * g[c4 * 4 + 1];
      acc += wv.z * g[c4 * 4 + 2];
      acc += wv.w * g[c4 * 4 + 3];
    }
    h1[o] = fmaxf(acc, 0.0f);
  }
  float h2[64];
#pragma unroll
  for (int o = 0; o < 64; ++o) {
    float acc = b1s[o];
    const uint2* wp = reinterpret_cast<const uint2*>(&W1s[o * 64]);
#pragma unroll
    for (int c4 = 0; c4 < 16; ++c4) {
      uint2 u = wp[c4];
      acc += __uint_as_float(u.x << 16) * h1[c4 * 4 + 0];
      acc += __uint_as_float(u.x & 0xFFFF0000u) * h1[c4 * 4 + 1];
      acc += __uint_as_float(u.y << 16) * h1[c4 * 4 + 2];
      acc += __uint_as_float(u.y & 0xFFFF0000u) * h1[c4 * 4 + 3];
    }
    h2[o] = fmaxf(acc, 0.0f);
  }
#pragma unroll 1
  for (int o = 0; o < 128; ++o) {
    float acc = b2s[o];
    const float4* wp = reinterpret_cast<const float4*>(&W2s[o * 64]);
#pragma unroll
    for (int c4 = 0; c4 < 16; ++c4) {
      float4 wv = wp[c4];
      acc += wv.x * h2[c4 * 4 + 0];
      acc += wv.y * h2[c4 * 4 + 1];
      acc += wv.z * h2[c4 * 4 + 2];
      acc += wv.w * h2[c4 * 4 + 3];
    }
    float v = fmaxf(acc, 0.0f);
#pragma unroll
    for (int off = 16; off >= 1; off >>= 1) v = fmaxf(v, __shfl_xor(v, off));
    if (s == 0) out_feat[((size_t)b * 128 + o) * NPOINT + c_local] = v;
  }
}

// ------------------------------------------------------------------- launch
extern "C" void kernel_launch(void* const* d_in, const int* in_sizes, int n_in,
                              void* d_out, int out_size, void* d_ws, size_t ws_size,
                              hipStream_t stream) {
  (void)n_in; (void)out_size;
  const float* xyz = (const float*)d_in[0];
  const float* feat = (const float*)d_in[1];
  // d_in[2] = num_points (8192, fixed by setup)
  const float* w0 = (const float*)d_in[3];
  const float* b0 = (const float*)d_in[4];
  const float* w1 = (const float*)d_in[5];
  const float* b1 = (const float*)d_in[6];
  const float* w2 = (const float*)d_in[7];
  const float* b2 = (const float*)d_in[8];

  const int Ntot = in_sizes[0] / 3;   // 65536
  const int B = Ntot / NPB;           // 8

  float* out = (float*)d_out;
  float* o_xyz = out;                                    // [B,512,3]
  float* o_idx = o_xyz + (size_t)B * NPOINT * 3;         // [B,512]
  float* o_feat = o_idx + (size_t)B * NPOINT;            // [B,128,512]
  float* o_sids = o_feat + (size_t)B * 128 * NPOINT;     // [B,512,32]

  // Workspace: only the transposed-features buffer (bf16), only if it fits.
  const size_t ft_bytes = (size_t)Ntot * 64 * 2;         // 8 MB
  const int useT = (ws_size >= ft_bytes) ? 1 : 0;
  unsigned short* ft_ws = (unsigned short*)d_ws;

  if (useT) {
    k_transpose<<<dim3(Ntot / 64), dim3(256), 0, stream>>>(feat, ft_ws, Ntot);
  }
  k_fps<<<dim3(B), dim3(512), 0, stream>>>(xyz, o_xyz, o_idx);
  k_ball<<<dim3(B * 64), dim3(512), 0, stream>>>(xyz, o_idx, o_sids);
  k_mlp<<<dim3(B * 64), dim3(256), 0, stream>>>(xyz, feat, ft_ws, o_idx, o_sids,
                                                w0, b0, w1, b1, w2, b2, o_feat,
                                                Ntot, useT);
}